// Round 1
// baseline (355.873 us; speedup 1.0000x reference)
//
#include <hip/hip_runtime.h>

// CTC loss forward (log-space), shapes fixed by the reference:
//   logits: (T, N, C) fp32 log-probs, labels: (N, S) int32 in [1, C),
//   prediction_sizes / target_sizes: (N,) int32.
// Decomposition: one 64-lane wave per batch item n. Lane i owns extended-
// lattice positions 2i (blank) and 2i+1 (label i). Even positions never
// take the diagonal skip, so the only cross-lane dependency per time step
// is the previous lane's odd alpha -> a single __shfl_up per step.

constexpr int T = 512, N = 256, C = 256, S = 48;
constexpr int L = 2 * S + 1;           // 97 lattice positions
#define NEGF (-1e30f)

__device__ __forceinline__ float lae2(float x, float y) {
  float m = fmaxf(x, y);
  float d = fminf(x, y) - m;           // <= 0; exp underflows cleanly for NEG
  return m + __logf(1.0f + __expf(d));
}

__device__ __forceinline__ float lae3(float x, float y, float z) {
  float m = fmaxf(fmaxf(x, y), z);
  float s = __expf(x - m) + __expf(y - m) + __expf(z - m);
  return m + __logf(s);
}

__launch_bounds__(64)
__global__ void ctc_alpha_kernel(const float* __restrict__ lp,
                                 const int*  __restrict__ labels,
                                 const int*  __restrict__ in_len,
                                 const int*  __restrict__ tgt_len,
                                 float* __restrict__ loss_ws) {
  const int n    = blockIdx.x;
  const int lane = threadIdx.x;

  // Per-lane label and skip_ok for odd position 2*lane+1.
  const int lab      = (lane < S) ? labels[n * S + lane] : 0;
  const int lab_prev = __shfl_up(lab, 1);
  // skip_ok[2i+1] = (ext!=0) && (ext != ext[2i-1]); for i==0 prev2 is the
  // zero pad -> reduces to (lab != 0).
  const bool skip = (lab != 0) && ((lane == 0) || (lab != lab_prev));
  const bool valid0 = (2 * lane     <= 2 * S);   // pos 2i     in [0, L)
  const bool valid1 = (2 * lane + 1 <= 2 * S);   // pos 2i + 1 in [0, L)
  const int Tin = in_len[n];
  const int tl  = tgt_len[n];

  const size_t stride = (size_t)N * C;           // row stride over t
  const float* row0 = lp + (size_t)n * C;        // lp[0][n][:]

  // alpha0: only positions 0 and 1 are live.
  float a0 = NEGF, a1 = NEGF;
  if (lane == 0) { a0 = row0[0]; a1 = row0[lab]; }

  // One-step-ahead prefetch of emissions (independent of the alpha chain).
  const float* rowp = row0 + stride;             // t = 1
  float lpb_n = rowp[0];
  float lpl_n = rowp[lab];

#pragma unroll 4
  for (int t = 1; t < T; ++t) {
    const float lpb = lpb_n, lpl = lpl_n;
    const float* nxt = rowp + stride;
    if (t + 1 < T) { lpb_n = nxt[0]; lpl_n = nxt[lab]; }
    rowp = nxt;

    float a1p = __shfl_up(a1, 1);
    if (lane == 0) a1p = NEGF;

    float na0 = lae2(a0, a1p) + lpb;                               // blank pos
    float na1 = (skip ? lae3(a1, a0, a1p) : lae2(a1, a0)) + lpl;   // label pos
    na0 = valid0 ? na0 : NEGF;
    na1 = valid1 ? na1 : NEGF;
    if (t < Tin) { a0 = na0; a1 = na1; }         // freeze past input length
  }

  // tails: alpha[2*tl-1] (lane tl-1, odd slot), alpha[2*tl] (lane tl, even slot)
  const float tail1 = __shfl(a1, tl - 1);
  const float tail2 = __shfl(a0, tl);
  if (lane == 0) {
    float loss = -lae2(tail1, tail2);
    if (!(loss <= 1e29f)) loss = 0.0f;           // zero_infinity (catches NaN too)
    loss_ws[n] = loss / (float)tl;
  }
}

__launch_bounds__(256)
__global__ void ctc_reduce_kernel(const float* __restrict__ loss_ws,
                                  float* __restrict__ out) {
  const int tid = threadIdx.x;
  float v = loss_ws[tid];
#pragma unroll
  for (int off = 32; off > 0; off >>= 1) v += __shfl_down(v, off);
  __shared__ float partial[4];
  if ((tid & 63) == 0) partial[tid >> 6] = v;
  __syncthreads();
  if (tid == 0) {
    float s = (partial[0] + partial[1] + partial[2] + partial[3]) / (float)N;
    if (isnan(s) || isinf(s)) s = 0.0f;          // final sanitize()
    out[0] = s;
  }
}

extern "C" void kernel_launch(void* const* d_in, const int* in_sizes, int n_in,
                              void* d_out, int out_size, void* d_ws, size_t ws_size,
                              hipStream_t stream) {
  const float* lp     = (const float*)d_in[0];   // (T, N, C) fp32
  const int*   labels = (const int*)d_in[1];     // (N, S)
  const int*   plen   = (const int*)d_in[2];     // (N,)
  const int*   tlen   = (const int*)d_in[3];     // (N,)
  float* ws  = (float*)d_ws;                     // N floats of scratch
  float* out = (float*)d_out;                    // scalar

  ctc_alpha_kernel<<<N, 64, 0, stream>>>(lp, labels, plen, tlen, ws);
  ctc_reduce_kernel<<<1, 256, 0, stream>>>(ws, out);
}

// Round 2
// 350.779 us; speedup vs baseline: 1.0145x; 1.0145x over previous
//
#include <hip/hip_runtime.h>

// CTC loss forward (log-space). logits (T,N,C) fp32 log-probs, labels (N,S)
// int32 in [1,C), prediction/target sizes (N,).
// One 64-lane wave per batch item n. Lane i owns extended-lattice positions
// 2i (blank) and 2i+1 (label i). Even positions never take the diagonal
// skip, so the only cross-lane dependency per step is lane i-1's odd alpha
// -> one DPP wave_shr1 per step (VALU pipe, no LDS round trip).
// Emission loads are independent of the alpha chain -> depth-12 register
// prefetch pipeline keeps 24 loads in flight per wave to hide ~900-cycle
// HBM latency at 1 wave/CU occupancy.

constexpr int T = 512, N = 256, C = 256, S = 48;
constexpr int D = 12;                  // prefetch depth (divides the main loop)
#define NEGF (-1e30f)

__device__ __forceinline__ float lae2(float x, float y) {
  float m = fmaxf(x, y);
  float d = fminf(x, y) - m;           // <= 0; exp underflows cleanly for NEG
  return m + __logf(1.0f + __expf(d));
}

__device__ __forceinline__ float lae3(float x, float y, float z) {
  float m = fmaxf(fmaxf(x, y), z);
  float s = __expf(x - m) + __expf(y - m) + __expf(z - m);
  return m + __logf(s);
}

// shuffle-up-by-1 via DPP wave_shr1 (0x138): lane i <- lane i-1, lane 0 <- fill.
__device__ __forceinline__ float wave_shr1(float v, float fill) {
  int r = __builtin_amdgcn_update_dpp(__float_as_int(fill), __float_as_int(v),
                                      0x138, 0xf, 0xf, false);
  return __int_as_float(r);
}

__launch_bounds__(64)
__global__ void ctc_alpha_kernel(const float* __restrict__ lp,
                                 const int*  __restrict__ labels,
                                 const int*  __restrict__ in_len,
                                 const int*  __restrict__ tgt_len,
                                 float* __restrict__ loss_ws) {
  const int n    = blockIdx.x;
  const int lane = threadIdx.x;

  const int lab      = (lane < S) ? labels[n * S + lane] : 0;
  const int lab_prev = __shfl_up(lab, 1);
  // skip_ok[2i+1] = (ext!=0) && (ext != ext[2i-1]); i==0 compares vs zero pad.
  const bool skip   = (lab != 0) && ((lane == 0) || (lab != lab_prev));
  const bool valid0 = (2 * lane     <= 2 * S);
  const bool valid1 = (2 * lane + 1 <= 2 * S);
  const int Tin = in_len[n];
  const int tl  = tgt_len[n];

  const size_t stride = (size_t)N * C;           // row stride over t
  const float* base = lp + (size_t)n * C;        // lp[0][n][:]

  float a0 = NEGF, a1 = NEGF;
  if (lane == 0) { a0 = base[0]; a1 = base[lab]; }

  // Prime the pipeline with rows t = 1..D.
  float pb[D], pl[D];
#pragma unroll
  for (int d = 0; d < D; ++d) {
    const float* row = base + (size_t)(1 + d) * stride;
    pb[d] = row[0];
    pl[d] = row[lab];
  }

  auto step = [&](int t, float lpb, float lpl) {
    float a1p = wave_shr1(a1, NEGF);
    float na0 = lae2(a0, a1p) + lpb;                               // blank pos
    float na1 = (skip ? lae3(a1, a0, a1p) : lae2(a1, a0)) + lpl;   // label pos
    na0 = valid0 ? na0 : NEGF;
    na1 = valid1 ? na1 : NEGF;
    const bool live = (t < Tin);                  // freeze past input length
    a0 = live ? na0 : a0;
    a1 = live ? na1 : a1;
  };

  // Main blocks: t in [tb, tb+D), fully unrolled so slot indices are static.
  int tb = 1;
  for (; tb + D <= T; tb += D) {
#pragma unroll
    for (int d = 0; d < D; ++d) {
      const int t = tb + d;
      const float lpb = pb[d], lpl = pl[d];
      if (t + D < T) {                            // refill slot with row t+D
        const float* row = base + (size_t)(t + D) * stride;
        pb[d] = row[0];
        pl[d] = row[lab];
      }
      step(t, lpb, lpl);
    }
  }
  // Epilogue: remaining steps consume already-loaded slots.
#pragma unroll
  for (int d = 0; d < (T - 1) % D; ++d) {
    const int t = tb + d;
    step(t, pb[d], pl[d]);
  }

  // tails: alpha[2*tl-1] (lane tl-1, odd slot), alpha[2*tl] (lane tl, even)
  const float tail1 = __shfl(a1, tl - 1);
  const float tail2 = __shfl(a0, tl);
  if (lane == 0) {
    float loss = -lae2(tail1, tail2);
    if (!(loss <= 1e29f)) loss = 0.0f;           // zero_infinity (catches NaN)
    loss_ws[n] = loss / (float)tl;
  }
}

__launch_bounds__(256)
__global__ void ctc_reduce_kernel(const float* __restrict__ loss_ws,
                                  float* __restrict__ out) {
  const int tid = threadIdx.x;
  float v = loss_ws[tid];
#pragma unroll
  for (int off = 32; off > 0; off >>= 1) v += __shfl_down(v, off);
  __shared__ float partial[4];
  if ((tid & 63) == 0) partial[tid >> 6] = v;
  __syncthreads();
  if (tid == 0) {
    float s = (partial[0] + partial[1] + partial[2] + partial[3]) / (float)N;
    if (isnan(s) || isinf(s)) s = 0.0f;          // final sanitize()
    out[0] = s;
  }
}

extern "C" void kernel_launch(void* const* d_in, const int* in_sizes, int n_in,
                              void* d_out, int out_size, void* d_ws, size_t ws_size,
                              hipStream_t stream) {
  const float* lp     = (const float*)d_in[0];   // (T, N, C) fp32
  const int*   labels = (const int*)d_in[1];     // (N, S)
  const int*   plen   = (const int*)d_in[2];     // (N,)
  const int*   tlen   = (const int*)d_in[3];     // (N,)
  float* ws  = (float*)d_ws;                     // N floats of scratch
  float* out = (float*)d_out;                    // scalar

  ctc_alpha_kernel<<<N, 64, 0, stream>>>(lp, labels, plen, tlen, ws);
  ctc_reduce_kernel<<<1, 256, 0, stream>>>(ws, out);
}

// Round 3
// 246.539 us; speedup vs baseline: 1.4435x; 1.4228x over previous
//
#include <hip/hip_runtime.h>

// CTC loss forward (log-space). logits (T,N,C) fp32 log-probs, labels (N,S)
// int32 in [1,C), prediction/target sizes (N,).
// One 64-lane wave per batch item n. Lane i owns extended-lattice positions
// 2i (blank) and 2i+1 (label i). Only cross-lane dep per step: lane i-1's
// odd alpha -> one DPP wave_shr1 (VALU pipe).
// Memory: triple-buffered register prefetch (A/B/C, depth 12). Refills are
// issued ~24 steps ahead of use; waiting on one buffer leaves the other two
// buffers' 48 loads in flight. __launch_bounds__(64,1) raises the VGPR
// budget to ~512 so the scheduler does NOT collapse the pipeline (R2 failed
// exactly here: VGPR_Count=24 proved the loads sank to their uses).

constexpr int T = 512, N = 256, C = 256, S = 48;
constexpr int D = 12;                  // buffer depth; 3 buffers
static_assert((T - 1) == 14 * 3 * D + 7, "schedule below hardcodes 14 rounds + 7 epilogue");
#define NEGF (-1e30f)

__device__ __forceinline__ float lae2(float x, float y) {
  float m = fmaxf(x, y);
  float d = fminf(x, y) - m;           // <= 0; exp underflows cleanly for NEG
  return m + __logf(1.0f + __expf(d));
}

__device__ __forceinline__ float lae3(float x, float y, float z) {
  float m = fmaxf(fmaxf(x, y), z);
  float s = __expf(x - m) + __expf(y - m) + __expf(z - m);
  return m + __logf(s);
}

// lane i <- lane i-1, lane 0 <- fill (DPP wave_shr1, 0x138)
__device__ __forceinline__ float wave_shr1(float v, float fill) {
  int r = __builtin_amdgcn_update_dpp(__float_as_int(fill), __float_as_int(v),
                                      0x138, 0xf, 0xf, false);
  return __int_as_float(r);
}

__launch_bounds__(64, 1)
__global__ void ctc_alpha_kernel(const float* __restrict__ lp,
                                 const int*  __restrict__ labels,
                                 const int*  __restrict__ in_len,
                                 const int*  __restrict__ tgt_len,
                                 float* __restrict__ loss_ws) {
  const int n    = blockIdx.x;
  const int lane = threadIdx.x;

  const int lab      = (lane < S) ? labels[n * S + lane] : 0;
  const int lab_prev = __shfl_up(lab, 1);
  // skip_ok[2i+1] = (ext!=0) && (ext != ext[2i-1]); i==0 compares vs zero pad.
  const bool skip   = (lab != 0) && ((lane == 0) || (lab != lab_prev));
  const bool valid0 = (2 * lane     <= 2 * S);
  const bool valid1 = (2 * lane + 1 <= 2 * S);
  const int Tin = in_len[n];
  const int tl  = tgt_len[n];

  const size_t stride = (size_t)N * C;           // row stride over t
  const float* base = lp + (size_t)n * C;        // lp[0][n][:]

  float a0 = NEGF, a1 = NEGF;
  if (lane == 0) { a0 = base[0]; a1 = base[lab]; }

  float Ab[D], Al[D], Bb[D], Bl[D], Cb[D], Cl[D];

  auto loadblk = [&](float* pb, float* pl, int t0) {
#pragma unroll
    for (int d = 0; d < D; ++d) {
      int t = t0 + d;
      t = (t < T) ? t : (T - 1);                 // clamp: junk rows never consumed
      const float* row = base + (size_t)t * stride;
      pb[d] = row[0];
      pl[d] = row[lab];
    }
  };

  auto step = [&](int t, float lpb, float lpl) {
    float a1p = wave_shr1(a1, NEGF);
    float na0 = lae2(a0, a1p) + lpb;                               // blank pos
    float na1 = (skip ? lae3(a1, a0, a1p) : lae2(a1, a0)) + lpl;   // label pos
    na0 = valid0 ? na0 : NEGF;
    na1 = valid1 ? na1 : NEGF;
    const bool live = (t < Tin);                  // freeze past input length
    a0 = live ? na0 : a0;
    a1 = live ? na1 : a1;
  };

  auto compblk = [&](const float* pb, const float* pl, int t0) {
#pragma unroll
    for (int d = 0; d < D; ++d) step(t0 + d, pb[d], pl[d]);
  };

  // Prime three blocks (72 loads in flight before first compute).
  loadblk(Ab, Al, 1);
  loadblk(Bb, Bl, 1 + D);
  loadblk(Cb, Cl, 1 + 2 * D);

  int tb = 1;
#pragma unroll 1
  for (int r = 0; r < 14; ++r) {
    compblk(Ab, Al, tb);           loadblk(Ab, Al, tb + 3 * D);
    compblk(Bb, Bl, tb + D);       loadblk(Bb, Bl, tb + 4 * D);
    compblk(Cb, Cl, tb + 2 * D);   loadblk(Cb, Cl, tb + 5 * D);
    tb += 3 * D;
  }
  // tb == 505; A holds t = 505..516 (clamped). Consume the last 7 steps.
#pragma unroll
  for (int d = 0; d < 7; ++d) step(tb + d, Ab[d], Al[d]);

  // tails: alpha[2*tl-1] (lane tl-1, odd slot), alpha[2*tl] (lane tl, even)
  const float tail1 = __shfl(a1, tl - 1);
  const float tail2 = __shfl(a0, tl);
  if (lane == 0) {
    float loss = -lae2(tail1, tail2);
    if (!(loss <= 1e29f)) loss = 0.0f;           // zero_infinity (catches NaN)
    loss_ws[n] = loss / (float)tl;
  }
}

__launch_bounds__(256)
__global__ void ctc_reduce_kernel(const float* __restrict__ loss_ws,
                                  float* __restrict__ out) {
  const int tid = threadIdx.x;
  float v = loss_ws[tid];
#pragma unroll
  for (int off = 32; off > 0; off >>= 1) v += __shfl_down(v, off);
  __shared__ float partial[4];
  if ((tid & 63) == 0) partial[tid >> 6] = v;
  __syncthreads();
  if (tid == 0) {
    float s = (partial[0] + partial[1] + partial[2] + partial[3]) / (float)N;
    if (isnan(s) || isinf(s)) s = 0.0f;          // final sanitize()
    out[0] = s;
  }
}

extern "C" void kernel_launch(void* const* d_in, const int* in_sizes, int n_in,
                              void* d_out, int out_size, void* d_ws, size_t ws_size,
                              hipStream_t stream) {
  const float* lp     = (const float*)d_in[0];   // (T, N, C) fp32
  const int*   labels = (const int*)d_in[1];     // (N, S)
  const int*   plen   = (const int*)d_in[2];     // (N,)
  const int*   tlen   = (const int*)d_in[3];     // (N,)
  float* ws  = (float*)d_ws;                     // N floats of scratch
  float* out = (float*)d_out;                    // scalar

  ctc_alpha_kernel<<<N, 64, 0, stream>>>(lp, labels, plen, tlen, ws);
  ctc_reduce_kernel<<<1, 256, 0, stream>>>(ws, out);
}